// Round 6
// baseline (85293.994 us; speedup 1.0000x reference)
//
#include <hip/hip_runtime.h>
#include <hip/hip_bf16.h>
#include <math.h>

typedef __hip_bfloat16 bf16;
using short4v = __attribute__((ext_vector_type(4))) short;
using short8 = __attribute__((ext_vector_type(8))) short;
using f32x4  = __attribute__((ext_vector_type(4))) float;

#define E_ 320
#define K_ 128
#define H_ 10
#define HD_ 32
#define T_ 256
#define TM1_ 255
#define SMAX_ (TM1_*K_)      // 32640
#define MAXCH_ 25
#define NBLK_ 256
#define QSCALE 0.17677669529663687f
#define EPS_LN 1e-5f

// ---- dtype-agnostic input load: isbf ? bf16 : f32 ----
__device__ __forceinline__ float ldin(const void* p, size_t i, int isbf){
  if (isbf) return __bfloat162float(((const bf16*)p)[i]);
  return ((const float*)p)[i];
}
__device__ __forceinline__ void stout(void* p, size_t i, float v, int isbf){
  if (isbf) ((bf16*)p)[i] = __float2bfloat16(v);
  else      ((float*)p)[i] = v;
}

// block = 320 threads (5 waves). Reduces a and b across the block.
__device__ __forceinline__ void reduce2_320(float& a, float& b, float* sc){
  #pragma unroll
  for (int off = 32; off > 0; off >>= 1){
    a += __shfl_down(a, off, 64);
    b += __shfl_down(b, off, 64);
  }
  int w = threadIdx.x >> 6, lane = threadIdx.x & 63;
  __syncthreads();
  if (lane == 0){ sc[w] = a; sc[8+w] = b; }
  __syncthreads();
  a = sc[0]+sc[1]+sc[2]+sc[3]+sc[4];
  b = sc[8]+sc[9]+sc[10]+sc[11]+sc[12];
}

// ---------------- dtype detector + barrier init ----------------
__global__ void detect_kernel(const void* __restrict__ mu0, int* __restrict__ flag,
                              unsigned* bar_cnt, unsigned* bar_gen){
  int lane = threadIdx.x;
  const unsigned short* u = (const unsigned short*)mu0;
  int cnt = 0;
  #pragma unroll
  for (int rep = 0; rep < 2; ++rep){
    unsigned short w = u[(size_t)(lane + rep*64) * 2];
    float v = __uint_as_float(((unsigned int)w) << 16);
    float a = fabsf(v);
    if (a >= 1e-4f && a <= 64.f) cnt++;
  }
  #pragma unroll
  for (int off = 32; off > 0; off >>= 1) cnt += __shfl_down(cnt, off, 64);
  if (lane == 0){
    *flag = (cnt >= 64) ? 1 : 0;
    *bar_cnt = 0u;
    *bar_gen = 0u;
  }
}

// ---------------- setup: fused projection weights (bf16, [n][k] layout) ----------------
__global__ __launch_bounds__(256) void setup_wc(const void* __restrict__ inw,
                                                const void* __restrict__ qkvw,
                                                bf16* __restrict__ WcB,
                                                const int* __restrict__ flagp){
  const int isbf = *flagp;
  int sec = blockIdx.z;
  int i = blockIdx.y*16 + threadIdx.y;   // contraction dim k
  int o = blockIdx.x*16 + threadIdx.x;   // output col within section
  __shared__ float As[16][17];
  __shared__ float Bs[16][17];
  float acc = 0.f;
  for (int mt = 0; mt < E_; mt += 16){
    As[threadIdx.y][threadIdx.x] = ldin(inw, ((size_t)(sec*E_ + blockIdx.x*16 + threadIdx.x))*E_ + mt + threadIdx.y, isbf);
    Bs[threadIdx.y][threadIdx.x] = ldin(qkvw, ((size_t)(sec*E_ + mt + threadIdx.x))*E_ + blockIdx.y*16 + threadIdx.y, isbf);
    __syncthreads();
    #pragma unroll
    for (int mm = 0; mm < 16; ++mm) acc += Bs[threadIdx.y][mm] * As[mm][threadIdx.x];
    __syncthreads();
  }
  if (sec == 0) acc *= QSCALE;
  WcB[((size_t)(sec*E_ + o))*E_ + i] = __float2bfloat16(acc);
}

__global__ __launch_bounds__(256) void setup_misc(const void* __restrict__ inw,
                                                  const void* __restrict__ inb,
                                                  const void* __restrict__ qkvb,
                                                  const void* __restrict__ outw,
                                                  const void* __restrict__ outb,
                                                  const void* __restrict__ lng,
                                                  const void* __restrict__ lnb,
                                                  float* __restrict__ bc,
                                                  bf16* __restrict__ owB,
                                                  float* __restrict__ vec,
                                                  const int* __restrict__ flagp){
  const int isbf = *flagp;
  int id = blockIdx.x*256 + threadIdx.x;
  if (id < 960){
    int sec = id / E_, o = id % E_;
    float acc = 0.f;
    for (int m = 0; m < E_; ++m)
      acc += ldin(inw, ((size_t)(sec*E_+o))*E_ + m, isbf) * ldin(qkvb, sec*E_ + m, isbf);
    acc += ldin(inb, id, isbf);
    if (sec == 0) acc *= QSCALE;
    bc[id] = acc;
  }
  int j = id - 1024;
  if (j >= 0 && j < E_*E_){
    owB[j] = __float2bfloat16(ldin(outw, j, isbf));
  }
  int v = id - (1024 + E_*E_);
  if (v >= 0 && v < 960){
    if (v < 320)       vec[v] = ldin(outb, v, isbf);
    else if (v < 640)  vec[v] = ldin(lng, v - 320, isbf);
    else               vec[v] = ldin(lnb, v - 640, isbf);
  }
}

// ---------------- alpha0 = LN(mu_0_alpha) ----------------
__global__ __launch_bounds__(320) void ln0_kernel(const void* __restrict__ mu0,
                                                  const float* __restrict__ vec,
                                                  float* __restrict__ alpha,
                                                  void* __restrict__ out,
                                                  const int* __restrict__ flagp){
  const int isbf = *flagp;
  int r = blockIdx.x, c = threadIdx.x;
  __shared__ float sc[16];
  float x = ldin(mu0, (size_t)r*E_ + c, isbf);
  float s = x, s2 = x*x;
  reduce2_320(s, s2, sc);
  float mean = s * (1.f/E_);
  float var  = s2 * (1.f/E_) - mean*mean;
  float y = (x - mean) * rsqrtf(var + EPS_LN) * vec[320 + c] + vec[640 + c];
  alpha[(size_t)r*E_ + c] = y;
  stout(out, (size_t)r*E_ + c, y, isbf);
}

// ---------------- grid barrier (device-scope, sense-reversing) ----------------
__device__ __forceinline__ void grid_barrier(unsigned* cnt, unsigned* gen){
  __syncthreads();                     // drains vmcnt for all block waves
  if (threadIdx.x == 0){
    __threadfence();                   // release: write back XCD L2
    unsigned g = __hip_atomic_load(gen, __ATOMIC_RELAXED, __HIP_MEMORY_SCOPE_AGENT);
    unsigned a = __hip_atomic_fetch_add(cnt, 1u, __ATOMIC_ACQ_REL, __HIP_MEMORY_SCOPE_AGENT);
    if (a == NBLK_ - 1u){
      __hip_atomic_store(cnt, 0u, __ATOMIC_RELAXED, __HIP_MEMORY_SCOPE_AGENT);
      __hip_atomic_fetch_add(gen, 1u, __ATOMIC_RELEASE, __HIP_MEMORY_SCOPE_AGENT);
    } else {
      while (__hip_atomic_load(gen, __ATOMIC_ACQUIRE, __HIP_MEMORY_SCOPE_AGENT) == g){
        __builtin_amdgcn_s_sleep(1);
      }
    }
    __threadfence();                   // acquire: invalidate stale lines
  }
  __syncthreads();
}

// LDS layout for the persistent kernel (42,624 B):
//   [0      .. 10496)  bf16 af[16][328]   (cp)    | bf16 pbuf[8][16][40] (attn, 10240 B)
//   [10496  .. 20992)  bf16 a2[16][328]
//   [20992  .. 41984)  f32  xbuf[16][328] (outproj) | f32 mlw[16][10][26] (merge, 16640 B)
//   [41984  .. 42624)  f32  mlL[16][10]
#define SM_A2   10496
#define SM_C    20992
#define SM_MLL  41984
#define SM_SIZE 42624

// ---- fused combine(t-1) + LN + project(t): executed by blocks with cg<3, rg<8 ----
__device__ __forceinline__ void cp_phase(int cg, int rg, int t, int nch,
                                         int do_combine, int do_project,
                                         const float* part, const bf16* owB, const bf16* WcB,
                                         const float* bc, const float* vec,
                                         const float* ain, float* aout, void* out, int isbf,
                                         bf16* q2b, bf16* kcb, bf16* vtb, char* smem){
  int tid = threadIdx.x;
  int w = tid >> 6, lane = tid & 63, cn = lane & 15, quad = lane >> 4;
  int r0 = rg*16;
  bf16 (*af)[328]   = (bf16(*)[328])(smem);
  bf16 (*a2)[328]   = (bf16(*)[328])(smem + SM_A2);
  float (*xbuf)[328]= (float(*)[328])(smem + SM_C);
  float (*mlw)[10][26] = (float(*)[10][26])(smem + SM_C);
  float (*mlL)[10]  = (float(*)[10])(smem + SM_MLL);

  if (do_combine){
    // --- stage 1: per-(row,head) chunk weights (ILP-4) ---
    if (tid < 160){
      int r = tid / 10, h = tid - 10*(tid/10);
      const float* pb = part + (((size_t)h*MAXCH_)*K_ + r0 + r)*36 + 32;  // ci stride 4608
      float m0=-INFINITY,m1=-INFINITY,m2=-INFINITY,m3=-INFINITY;
      int ci = 0;
      for (; ci + 4 <= nch; ci += 4){
        m0 = fmaxf(m0, pb[(ci+0)*4608]);
        m1 = fmaxf(m1, pb[(ci+1)*4608]);
        m2 = fmaxf(m2, pb[(ci+2)*4608]);
        m3 = fmaxf(m3, pb[(ci+3)*4608]);
      }
      for (; ci < nch; ++ci) m0 = fmaxf(m0, pb[ci*4608]);
      float mst = fmaxf(fmaxf(m0,m1), fmaxf(m2,m3));
      float L0=0.f, L1=0.f, L2=0.f, L3=0.f;
      ci = 0;
      for (; ci + 4 <= nch; ci += 4){
        float2 mlv0 = *(const float2*)(pb + (ci+0)*4608);
        float2 mlv1 = *(const float2*)(pb + (ci+1)*4608);
        float2 mlv2 = *(const float2*)(pb + (ci+2)*4608);
        float2 mlv3 = *(const float2*)(pb + (ci+3)*4608);
        float w0=__expf(mlv0.x-mst), w1=__expf(mlv1.x-mst), w2=__expf(mlv2.x-mst), w3=__expf(mlv3.x-mst);
        mlw[r][h][ci+0]=w0; mlw[r][h][ci+1]=w1; mlw[r][h][ci+2]=w2; mlw[r][h][ci+3]=w3;
        L0 += w0*mlv0.y; L1 += w1*mlv1.y; L2 += w2*mlv2.y; L3 += w3*mlv3.y;
      }
      for (; ci < nch; ++ci){
        float2 mlv = *(const float2*)(pb + ci*4608);
        float wg = __expf(mlv.x - mst);
        mlw[r][h][ci] = wg; L0 += wg*mlv.y;
      }
      mlL[r][h] = (L0+L1)+(L2+L3);
    }
    __syncthreads();

    // --- stage 2: merge partial O (pairs of elems, ILP-8) ---
    #pragma unroll
    for (int k = 0; k < 5; ++k){
      int e1 = tid + (2*k)*512, e2 = tid + (2*k+1)*512;
      int r1 = e1/320, c1 = e1 - 320*r1, h1 = c1 >> 5, d1 = c1 & 31;
      int r2 = e2/320, c2 = e2 - 320*r2, h2 = c2 >> 5, d2 = c2 & 31;
      const float* p1 = part + (((size_t)h1*MAXCH_)*K_ + r0 + r1)*36 + d1;
      const float* p2 = part + (((size_t)h2*MAXCH_)*K_ + r0 + r2)*36 + d2;
      float a0=0.f,a1=0.f,a2_=0.f,a3=0.f,b0=0.f,b1=0.f,b2=0.f,b3=0.f;
      int ci = 0;
      for (; ci + 4 <= nch; ci += 4){
        a0 += mlw[r1][h1][ci+0]*p1[(ci+0)*4608];
        a1 += mlw[r1][h1][ci+1]*p1[(ci+1)*4608];
        a2_+= mlw[r1][h1][ci+2]*p1[(ci+2)*4608];
        a3 += mlw[r1][h1][ci+3]*p1[(ci+3)*4608];
        b0 += mlw[r2][h2][ci+0]*p2[(ci+0)*4608];
        b1 += mlw[r2][h2][ci+1]*p2[(ci+1)*4608];
        b2 += mlw[r2][h2][ci+2]*p2[(ci+2)*4608];
        b3 += mlw[r2][h2][ci+3]*p2[(ci+3)*4608];
      }
      for (; ci < nch; ++ci){
        a0 += mlw[r1][h1][ci]*p1[ci*4608];
        b0 += mlw[r2][h2][ci]*p2[ci*4608];
      }
      af[r1][c1] = __float2bfloat16(((a0+a1)+(a2_+a3)) / mlL[r1][h1]);
      af[r2][c2] = __float2bfloat16(((b0+b1)+(b2+b3)) / mlL[r2][h2]);
    }
    __syncthreads();

    // --- out-proj MFMA: xbuf(16x320) = af . out_w^T + outb + residual ---
    {
      f32x4 acc[3]; int ntv[3]; int ntc = 0;
      for (int nt = w; nt < 20; nt += 8){ ntv[ntc] = nt; acc[ntc] = (f32x4){0.f,0.f,0.f,0.f}; ntc++; }
      for (int kk = 0; kk < 10; ++kk){
        short8 afr = *(const short8*)(const void*)(&af[cn][kk*32 + quad*8]);
        for (int i = 0; i < ntc; ++i){
          short8 bfr = *(const short8*)(const void*)(owB + ((size_t)(ntv[i]*16 + cn))*E_ + kk*32 + quad*8);
          acc[i] = __builtin_amdgcn_mfma_f32_16x16x32_bf16(afr, bfr, acc[i], 0, 0, 0);
        }
      }
      __syncthreads();   // af fully read; xbuf region (overlaying mlw) now writable
      for (int i = 0; i < ntc; ++i){
        int col = ntv[i]*16 + cn;
        #pragma unroll
        for (int rr = 0; rr < 4; ++rr){
          int lr = quad*4 + rr;
          xbuf[lr][col] = acc[i][rr] + vec[col] + ain[(size_t)(r0+lr)*E_ + col];
        }
      }
    }
    __syncthreads();

    // --- LN per row ---
    {
      int lr = tid >> 5;
      int j32 = tid & 31;
      float s = 0.f, s2 = 0.f;
      for (int c = j32; c < E_; c += 32){ float x = xbuf[lr][c]; s += x; s2 += x*x; }
      #pragma unroll
      for (int off = 1; off < 32; off <<= 1){
        s  += __shfl_xor(s, off, 32);
        s2 += __shfl_xor(s2, off, 32);
      }
      float mean = s * (1.f/E_);
      float var  = s2 * (1.f/E_) - mean*mean;
      float rs = rsqrtf(var + EPS_LN);
      for (int c = j32; c < E_; c += 32){
        float y = (xbuf[lr][c] - mean) * rs * vec[320 + c] + vec[640 + c];
        a2[lr][c] = __float2bfloat16(y);
        if (cg == 0){
          aout[(size_t)(r0+lr)*E_ + c] = y;
          stout(out, ((size_t)t*K_ + r0 + lr)*E_ + c, y, isbf);
        }
      }
    }
    __syncthreads();
  } else {
    // t == 0: alpha straight from ln0
    for (int v = tid; v < 16*E_; v += 512){
      int r = v / E_, e = v - E_*(v/E_);
      a2[r][e] = __float2bfloat16(ain[(size_t)(r0+r)*E_ + e]);
    }
    __syncthreads();
  }

  if (!do_project) return;

  // --- project MFMA: this cg's 320 of the 960 output cols ---
  {
    f32x4 acc[3]; int ntv[3]; int ntc = 0;
    for (int nt = w; nt < 20; nt += 8){ ntv[ntc] = nt; acc[ntc] = (f32x4){0.f,0.f,0.f,0.f}; ntc++; }
    for (int kk = 0; kk < 10; ++kk){
      short8 afr = *(const short8*)(const void*)(&a2[cn][kk*32 + quad*8]);
      for (int i = 0; i < ntc; ++i){
        short8 bfr = *(const short8*)(const void*)(WcB + ((size_t)(cg*E_ + ntv[i]*16 + cn))*E_ + kk*32 + quad*8);
        acc[i] = __builtin_amdgcn_mfma_f32_16x16x32_bf16(afr, bfr, acc[i], 0, 0, 0);
      }
    }
    for (int i = 0; i < ntc; ++i){
      int coll = ntv[i]*16 + cn;
      float bias = bc[cg*E_ + coll];
      if (cg == 0){
        #pragma unroll
        for (int rr = 0; rr < 4; ++rr)
          q2b[(size_t)(r0 + quad*4 + rr)*E_ + coll] = __float2bfloat16(acc[i][rr] + bias);
      } else if (cg == 1){
        #pragma unroll
        for (int rr = 0; rr < 4; ++rr)
          kcb[((size_t)(t*K_ + r0 + quad*4 + rr))*E_ + coll] = __float2bfloat16(acc[i][rr] + bias);
      } else {
        union { short4v v; bf16 e[4]; } u;
        #pragma unroll
        for (int rr = 0; rr < 4; ++rr) u.e[rr] = __float2bfloat16(acc[i][rr] + bias);
        *(short4v*)(void*)(vtb + (size_t)coll*SMAX_ + t*K_ + r0 + quad*4) = u.v;
      }
    }
  }
}

// ---- one attention cell (ci,h): 8 waves, wave w owns q-tile w ----
__device__ __forceinline__ void attn_cell(int ci, int h, const bf16* q2b, const bf16* kcb,
                                          const bf16* vtb, float* part, int S, int chunkS,
                                          char* smem){
  int w    = threadIdx.x >> 6;
  int lane = threadIdx.x & 63;
  int cn   = lane & 15;
  int quad = lane >> 4;
  bf16 (*pbuf)[40] = (bf16(*)[40])(smem + w*16*40*2);

  int s0 = ci*chunkS, s1 = min(s0 + chunkS, S);

  short8 qf = *(const short8*)(const void*)(q2b + (size_t)(w*16 + cn)*E_ + h*HD_ + quad*8);

  f32x4 accT[2];
  accT[0] = (f32x4){0.f,0.f,0.f,0.f};
  accT[1] = (f32x4){0.f,0.f,0.f,0.f};
  float mcol = -INFINITY, lcol = 0.f;

  for (int sb = s0; sb < s1; sb += 32){
    short8 kf0 = *(const short8*)(const void*)(kcb + (size_t)(sb +      cn)*E_ + h*HD_ + quad*8);
    short8 kf1 = *(const short8*)(const void*)(kcb + (size_t)(sb + 16 + cn)*E_ + h*HD_ + quad*8);
    short8 vf0 = *(const short8*)(const void*)(vtb + (size_t)(h*HD_ +      cn)*SMAX_ + sb + quad*8);
    short8 vf1 = *(const short8*)(const void*)(vtb + (size_t)(h*HD_ + 16 + cn)*SMAX_ + sb + quad*8);
    f32x4 z = (f32x4){0.f,0.f,0.f,0.f};
    f32x4 sT0 = __builtin_amdgcn_mfma_f32_16x16x32_bf16(kf0, qf, z, 0, 0, 0);
    f32x4 sT1 = __builtin_amdgcn_mfma_f32_16x16x32_bf16(kf1, qf, z, 0, 0, 0);

    float mx = fmaxf(fmaxf(fmaxf(sT0[0], sT0[1]), fmaxf(sT0[2], sT0[3])),
                     fmaxf(fmaxf(sT1[0], sT1[1]), fmaxf(sT1[2], sT1[3])));
    mx = fmaxf(mx, __shfl_xor(mx, 16, 64));
    mx = fmaxf(mx, __shfl_xor(mx, 32, 64));
    float mn = fmaxf(mcol, mx);
    float corr = __expf(mcol - mn);
    mcol = mn;

    float p0[4], p1[4];
    #pragma unroll
    for (int r = 0; r < 4; ++r){ p0[r] = __expf(sT0[r] - mn); p1[r] = __expf(sT1[r] - mn); }
    float ps = (p0[0]+p0[1]) + (p0[2]+p0[3]) + (p1[0]+p1[1]) + (p1[2]+p1[3]);
    ps += __shfl_xor(ps, 16, 64);
    ps += __shfl_xor(ps, 32, 64);
    lcol = lcol*corr + ps;
    accT[0] *= corr;
    accT[1] *= corr;

    union { short4v v; bf16 e[4]; } u0, u1;
    #pragma unroll
    for (int r = 0; r < 4; ++r){ u0.e[r] = __float2bfloat16(p0[r]); u1.e[r] = __float2bfloat16(p1[r]); }
    *(short4v*)(void*)(&pbuf[cn][quad*4])      = u0.v;
    *(short4v*)(void*)(&pbuf[cn][16 + quad*4]) = u1.v;
    asm volatile("s_waitcnt lgkmcnt(0)" ::: "memory");
    short8 pf = *(const short8*)(const void*)(&pbuf[cn][quad*8]);
    accT[0] = __builtin_amdgcn_mfma_f32_16x16x32_bf16(vf0, pf, accT[0], 0, 0, 0);
    accT[1] = __builtin_amdgcn_mfma_f32_16x16x32_bf16(vf1, pf, accT[1], 0, 0, 0);
  }

  size_t base = (((size_t)h*MAXCH_ + ci)*K_ + 16*w + cn)*36;
  *(f32x4*)(part + base + quad*4)      = accT[0];
  *(f32x4*)(part + base + 16 + quad*4) = accT[1];
  if (quad == 0){ part[base + 32] = mcol; part[base + 33] = lcol; }
}

// ---------------- persistent scan kernel: 256 blocks x 512 threads ----------------
__global__ __launch_bounds__(512) void mega_kernel(const bf16* WcB, const bf16* owB,
                                                   const float* bc, const float* vec,
                                                   float* abuf0, float* abuf1,
                                                   float* part, const int* flagp,
                                                   bf16* q2b, bf16* kcb, bf16* vtb,
                                                   void* out,
                                                   unsigned* bar_cnt, unsigned* bar_gen){
  __shared__ __align__(16) char smem[SM_SIZE];
  const int isbf = *flagp;
  int b = blockIdx.x;
  int cg = b / 8, rg = b - 8*(b/8);   // for b<24

  int nch_prev = 0;
  for (int t = 0; t < TM1_; ++t){
    const float* ain = (t == 0) ? abuf0 : ((t & 1) ? abuf0 : abuf1);
    float* aout = (t & 1) ? abuf1 : abuf0;
    if (b < 24)
      cp_phase(cg, rg, t, nch_prev, (t > 0) ? 1 : 0, 1,
               part, owB, WcB, bc, vec, ain, aout, out, isbf, q2b, kcb, vtb, smem);
    grid_barrier(bar_cnt, bar_gen);

    int S = (t+1)*K_;
    int nch = (S + 127) / 128; if (nch > MAXCH_) nch = MAXCH_;
    int chunkS = (((S + nch - 1)/nch) + 31) / 32 * 32;
    int nchU = (S + chunkS - 1) / chunkS;
    if (b < nchU*10)
      attn_cell(b/10, b - 10*(b/10), q2b, kcb, vtb, part, S, chunkS, smem);
    grid_barrier(bar_cnt, bar_gen);
    nch_prev = nchU;
  }
  // final combine: alpha(255) -> out rows 255*K (blocks 0..7, cg==0)
  if (b < 8){
    const float* ain = abuf0;   // alpha(254): t=254 even -> aout was abuf0
    float* aout = abuf1;
    cp_phase(0, b, TM1_, nch_prev, 1, 0,
             part, owB, WcB, bc, vec, ain, aout, out, isbf, q2b, kcb, vtb, smem);
  }
}

extern "C" void kernel_launch(void* const* d_in, const int* in_sizes, int n_in,
                              void* d_out, int out_size, void* d_ws, size_t ws_size,
                              hipStream_t stream){
  const void* mu0  = d_in[0];
  const void* qkvw = d_in[1];
  const void* qkvb = d_in[2];
  const void* inw  = d_in[3];
  const void* inb  = d_in[4];
  const void* outw = d_in[5];
  const void* outb = d_in[6];
  const void* lng  = d_in[7];
  const void* lnb  = d_in[8];
  float* ws = (float*)d_ws;

  // ws layout (float offsets), all 16B-aligned
  const size_t O_WCB    = 0;         // 960x320 bf16 = 153600 f
  const size_t O_OWB    = 153600;    // 320x320 bf16 = 51200 f
  const size_t O_BC     = 204800;    // 1024
  const size_t O_VEC    = 205824;    // 1024
  const size_t O_A0     = 206848;    // 40960
  const size_t O_A1     = 247808;    // 40960
  const size_t O_PART   = 288768;    // 10*25*128*36 = 1152000
  const size_t O_FLAG   = 1440768;   // flag @0, bar_cnt @32, bar_gen @64 (separate lines)
  const size_t O_Q2     = 1440864;   // 128*320 bf16 = 20480 f
  const size_t O_KC     = 1461344;   // SMAX*320 bf16 = 5222400 f
  const size_t O_VT     = 6683744;   // SMAX*320 bf16 = 5222400 f
  // end = 11906144 floats = 47.6 MB

  bf16*  WcB   = (bf16*)(ws + O_WCB);
  bf16*  owB   = (bf16*)(ws + O_OWB);
  float* bc    = ws + O_BC;
  float* vec   = ws + O_VEC;
  float* abuf0 = ws + O_A0;
  float* abuf1 = ws + O_A1;
  float* part  = ws + O_PART;
  int*   flag  = (int*)(ws + O_FLAG);
  unsigned* bar_cnt = (unsigned*)(ws + O_FLAG + 32);
  unsigned* bar_gen = (unsigned*)(ws + O_FLAG + 64);
  bf16*  q2b   = (bf16*)(ws + O_Q2);
  bf16*  kcb   = (bf16*)(ws + O_KC);
  bf16*  vtb   = (bf16*)(ws + O_VT);

  detect_kernel<<<dim3(1), dim3(64), 0, stream>>>(mu0, flag, bar_cnt, bar_gen);
  setup_wc<<<dim3(20,20,3), dim3(16,16), 0, stream>>>(inw, qkvw, WcB, flag);
  setup_misc<<<dim3(408), dim3(256), 0, stream>>>(inw, inb, qkvb, outw, outb, lng, lnb, bc, owB, vec, flag);
  ln0_kernel<<<dim3(128), dim3(320), 0, stream>>>(mu0, vec, abuf0, d_out, flag);
  mega_kernel<<<dim3(NBLK_), dim3(512), 0, stream>>>(WcB, owB, bc, vec, abuf0, abuf1,
                                                     part, flag, q2b, kcb, vtb, d_out,
                                                     bar_cnt, bar_gen);
}

// Round 7
// 17519.733 us; speedup vs baseline: 4.8685x; 4.8685x over previous
//
#include <hip/hip_runtime.h>
#include <hip/hip_bf16.h>
#include <math.h>

typedef __hip_bfloat16 bf16;
using short4v = __attribute__((ext_vector_type(4))) short;
using short8 = __attribute__((ext_vector_type(8))) short;
using f32x4  = __attribute__((ext_vector_type(4))) float;

#define E_ 320
#define K_ 128
#define H_ 10
#define HD_ 32
#define T_ 256
#define TM1_ 255
#define SMAX_ (TM1_*K_)      // 32640
#define MAXCH_ 25
#define NBLK_ 256
#define QSCALE 0.17677669529663687f
#define EPS_LN 1e-5f

// ---- system-coherent (LLC) access helpers: bypass L1+L2 via sc0 sc1 ----
// Used ONLY for cross-phase mutable buffers inside the persistent kernel:
// part, q2b, alpha (ld+st) and kcb/vtb (st only; their rows are write-once
// and never read before written, so reads stay normal-cached for L2 reuse).
#define LD1(d,p)  asm volatile("global_load_dword %0, %1, off sc0 sc1"   : "=v"(d) : "v"(p))
#define LD2(d,p)  asm volatile("global_load_dwordx2 %0, %1, off sc0 sc1" : "=v"(d) : "v"(p))
#define LD4(d,p)  asm volatile("global_load_dwordx4 %0, %1, off sc0 sc1" : "=v"(d) : "v"(p))
#define WD1(a)            asm volatile("s_waitcnt vmcnt(0)" : "+v"(a) :: "memory")
#define WD2(a,b)          asm volatile("s_waitcnt vmcnt(0)" : "+v"(a),"+v"(b) :: "memory")
#define WD4(a,b,c,d)      asm volatile("s_waitcnt vmcnt(0)" : "+v"(a),"+v"(b),"+v"(c),"+v"(d) :: "memory")
#define WD8(a,b,c,d,e,f,g,h) asm volatile("s_waitcnt vmcnt(0)" : "+v"(a),"+v"(b),"+v"(c),"+v"(d),"+v"(e),"+v"(f),"+v"(g),"+v"(h) :: "memory")

__device__ __forceinline__ void st_sc_f32(float* p, float v){
  asm volatile("global_store_dword %0, %1, off sc0 sc1" :: "v"(p), "v"(v) : "memory");
}
__device__ __forceinline__ void st_sc_f32x4(float* p, f32x4 v){
  asm volatile("global_store_dwordx4 %0, %1, off sc0 sc1" :: "v"(p), "v"(v) : "memory");
}
__device__ __forceinline__ void st_sc_b64(void* p, short4v v){
  asm volatile("global_store_dwordx2 %0, %1, off sc0 sc1" :: "v"(p), "v"(v) : "memory");
}
__device__ __forceinline__ void st_sc_bf16(bf16* p, float v){
  bf16 b = __float2bfloat16(v);
  unsigned u = *(const unsigned short*)&b;
  asm volatile("global_store_short %0, %1, off sc0 sc1" :: "v"(p), "v"(u) : "memory");
}

// ---- dtype-agnostic input load: isbf ? bf16 : f32 ----
__device__ __forceinline__ float ldin(const void* p, size_t i, int isbf){
  if (isbf) return __bfloat162float(((const bf16*)p)[i]);
  return ((const float*)p)[i];
}
__device__ __forceinline__ void stout(void* p, size_t i, float v, int isbf){
  if (isbf) ((bf16*)p)[i] = __float2bfloat16(v);
  else      ((float*)p)[i] = v;
}

// block = 320 threads (5 waves). Reduces a and b across the block.
__device__ __forceinline__ void reduce2_320(float& a, float& b, float* sc){
  #pragma unroll
  for (int off = 32; off > 0; off >>= 1){
    a += __shfl_down(a, off, 64);
    b += __shfl_down(b, off, 64);
  }
  int w = threadIdx.x >> 6, lane = threadIdx.x & 63;
  __syncthreads();
  if (lane == 0){ sc[w] = a; sc[8+w] = b; }
  __syncthreads();
  a = sc[0]+sc[1]+sc[2]+sc[3]+sc[4];
  b = sc[8]+sc[9]+sc[10]+sc[11]+sc[12];
}

// ---------------- dtype detector + barrier init ----------------
__global__ void detect_kernel(const void* __restrict__ mu0, int* __restrict__ flag,
                              unsigned* bar_cnt, unsigned* bar_gen){
  int lane = threadIdx.x;
  const unsigned short* u = (const unsigned short*)mu0;
  int cnt = 0;
  #pragma unroll
  for (int rep = 0; rep < 2; ++rep){
    unsigned short w = u[(size_t)(lane + rep*64) * 2];
    float v = __uint_as_float(((unsigned int)w) << 16);
    float a = fabsf(v);
    if (a >= 1e-4f && a <= 64.f) cnt++;
  }
  #pragma unroll
  for (int off = 32; off > 0; off >>= 1) cnt += __shfl_down(cnt, off, 64);
  if (lane == 0){
    *flag = (cnt >= 64) ? 1 : 0;
    *bar_cnt = 0u;
    *bar_gen = 0u;
  }
}

// ---------------- setup: fused projection weights (bf16, [n][k] layout) ----------------
__global__ __launch_bounds__(256) void setup_wc(const void* __restrict__ inw,
                                                const void* __restrict__ qkvw,
                                                bf16* __restrict__ WcB,
                                                const int* __restrict__ flagp){
  const int isbf = *flagp;
  int sec = blockIdx.z;
  int i = blockIdx.y*16 + threadIdx.y;   // contraction dim k
  int o = blockIdx.x*16 + threadIdx.x;   // output col within section
  __shared__ float As[16][17];
  __shared__ float Bs[16][17];
  float acc = 0.f;
  for (int mt = 0; mt < E_; mt += 16){
    As[threadIdx.y][threadIdx.x] = ldin(inw, ((size_t)(sec*E_ + blockIdx.x*16 + threadIdx.x))*E_ + mt + threadIdx.y, isbf);
    Bs[threadIdx.y][threadIdx.x] = ldin(qkvw, ((size_t)(sec*E_ + mt + threadIdx.x))*E_ + blockIdx.y*16 + threadIdx.y, isbf);
    __syncthreads();
    #pragma unroll
    for (int mm = 0; mm < 16; ++mm) acc += Bs[threadIdx.y][mm] * As[mm][threadIdx.x];
    __syncthreads();
  }
  if (sec == 0) acc *= QSCALE;
  WcB[((size_t)(sec*E_ + o))*E_ + i] = __float2bfloat16(acc);
}

__global__ __launch_bounds__(256) void setup_misc(const void* __restrict__ inw,
                                                  const void* __restrict__ inb,
                                                  const void* __restrict__ qkvb,
                                                  const void* __restrict__ outw,
                                                  const void* __restrict__ outb,
                                                  const void* __restrict__ lng,
                                                  const void* __restrict__ lnb,
                                                  float* __restrict__ bc,
                                                  bf16* __restrict__ owB,
                                                  float* __restrict__ vec,
                                                  const int* __restrict__ flagp){
  const int isbf = *flagp;
  int id = blockIdx.x*256 + threadIdx.x;
  if (id < 960){
    int sec = id / E_, o = id % E_;
    float acc = 0.f;
    for (int m = 0; m < E_; ++m)
      acc += ldin(inw, ((size_t)(sec*E_+o))*E_ + m, isbf) * ldin(qkvb, sec*E_ + m, isbf);
    acc += ldin(inb, id, isbf);
    if (sec == 0) acc *= QSCALE;
    bc[id] = acc;
  }
  int j = id - 1024;
  if (j >= 0 && j < E_*E_){
    owB[j] = __float2bfloat16(ldin(outw, j, isbf));
  }
  int v = id - (1024 + E_*E_);
  if (v >= 0 && v < 960){
    if (v < 320)       vec[v] = ldin(outb, v, isbf);
    else if (v < 640)  vec[v] = ldin(lng, v - 320, isbf);
    else               vec[v] = ldin(lnb, v - 640, isbf);
  }
}

// ---------------- alpha0 = LN(mu_0_alpha) ----------------
__global__ __launch_bounds__(320) void ln0_kernel(const void* __restrict__ mu0,
                                                  const float* __restrict__ vec,
                                                  float* __restrict__ alpha,
                                                  void* __restrict__ out,
                                                  const int* __restrict__ flagp){
  const int isbf = *flagp;
  int r = blockIdx.x, c = threadIdx.x;
  __shared__ float sc[16];
  float x = ldin(mu0, (size_t)r*E_ + c, isbf);
  float s = x, s2 = x*x;
  reduce2_320(s, s2, sc);
  float mean = s * (1.f/E_);
  float var  = s2 * (1.f/E_) - mean*mean;
  float y = (x - mean) * rsqrtf(var + EPS_LN) * vec[320 + c] + vec[640 + c];
  alpha[(size_t)r*E_ + c] = y;
  stout(out, (size_t)r*E_ + c, y, isbf);
}

// ---------------- grid barrier: all-relaxed atomics at the LLC ----------------
// No fences / no L2 invalidates. Cross-phase data uses sc0|sc1 (LLC) accesses,
// so the only ordering needed is: stores drained (vmcnt 0, done by __syncthreads)
// before arrive; cnt reset drained before gen bump.
__device__ __forceinline__ void grid_barrier(unsigned* cnt, unsigned* gen){
  __syncthreads();
  if (threadIdx.x == 0){
    unsigned g = __hip_atomic_load(gen, __ATOMIC_RELAXED, __HIP_MEMORY_SCOPE_AGENT);
    unsigned a = __hip_atomic_fetch_add(cnt, 1u, __ATOMIC_RELAXED, __HIP_MEMORY_SCOPE_AGENT);
    if (a == NBLK_ - 1u){
      __hip_atomic_store(cnt, 0u, __ATOMIC_RELAXED, __HIP_MEMORY_SCOPE_AGENT);
      asm volatile("s_waitcnt vmcnt(0)" ::: "memory");
      __hip_atomic_store(gen, g + 1u, __ATOMIC_RELAXED, __HIP_MEMORY_SCOPE_AGENT);
    } else {
      while (__hip_atomic_load(gen, __ATOMIC_RELAXED, __HIP_MEMORY_SCOPE_AGENT) == g)
        __builtin_amdgcn_s_sleep(8);
    }
  }
  __syncthreads();
}

// LDS layout (42,624 B): see R5.
#define SM_A2   10496
#define SM_C    20992
#define SM_MLL  41984
#define SM_SIZE 42624

// ---- fused combine(t-1) + LN + project(t) ----
__device__ __forceinline__ void cp_phase(int cg, int rg, int t, int nch,
                                         int do_combine, int do_project,
                                         const float* part, const bf16* owB, const bf16* WcB,
                                         const float* bc, const float* vec,
                                         const float* ain, float* aout, void* out, int isbf,
                                         bf16* q2b, bf16* kcb, bf16* vtb, char* smem){
  int tid = threadIdx.x;
  int w = tid >> 6, lane = tid & 63, cn = lane & 15, quad = lane >> 4;
  int r0 = rg*16;
  bf16 (*af)[328]   = (bf16(*)[328])(smem);
  bf16 (*a2)[328]   = (bf16(*)[328])(smem + SM_A2);
  float (*xbuf)[328]= (float(*)[328])(smem + SM_C);
  float (*mlw)[10][26] = (float(*)[10][26])(smem + SM_C);
  float (*mlL)[10]  = (float(*)[10])(smem + SM_MLL);

  if (do_combine){
    // --- stage 1: per-(row,head) chunk weights (batched sc01 loads) ---
    if (tid < 160){
      int r = tid / 10, h = tid - 10*(tid/10);
      const float* pb = part + (((size_t)h*MAXCH_)*K_ + r0 + r)*36 + 32;  // ci stride 4608
      float m0=-INFINITY,m1=-INFINITY,m2=-INFINITY,m3=-INFINITY;
      int ci = 0;
      for (; ci + 4 <= nch; ci += 4){
        float t0,t1,t2,t3;
        LD1(t0, pb + (ci+0)*4608); LD1(t1, pb + (ci+1)*4608);
        LD1(t2, pb + (ci+2)*4608); LD1(t3, pb + (ci+3)*4608);
        WD4(t0,t1,t2,t3);
        m0=fmaxf(m0,t0); m1=fmaxf(m1,t1); m2=fmaxf(m2,t2); m3=fmaxf(m3,t3);
      }
      for (; ci < nch; ++ci){ float t0; LD1(t0, pb + ci*4608); WD1(t0); m0=fmaxf(m0,t0); }
      float mst = fmaxf(fmaxf(m0,m1), fmaxf(m2,m3));
      float L0=0.f, L1=0.f, L2=0.f, L3=0.f;
      ci = 0;
      for (; ci + 4 <= nch; ci += 4){
        float2 v0,v1,v2,v3;
        LD2(v0, pb + (ci+0)*4608); LD2(v1, pb + (ci+1)*4608);
        LD2(v2, pb + (ci+2)*4608); LD2(v3, pb + (ci+3)*4608);
        WD4(v0,v1,v2,v3);
        float w0=__expf(v0.x-mst), w1=__expf(v1.x-mst), w2=__expf(v2.x-mst), w3=__expf(v3.x-mst);
        mlw[r][h][ci+0]=w0; mlw[r][h][ci+1]=w1; mlw[r][h][ci+2]=w2; mlw[r][h][ci+3]=w3;
        L0 += w0*v0.y; L1 += w1*v1.y; L2 += w2*v2.y; L3 += w3*v3.y;
      }
      for (; ci < nch; ++ci){
        float2 v0; LD2(v0, pb + ci*4608); WD1(v0);
        float wg = __expf(v0.x - mst);
        mlw[r][h][ci] = wg; L0 += wg*v0.y;
      }
      mlL[r][h] = (L0+L1)+(L2+L3);
    }
    __syncthreads();

    // --- stage 2: merge partial O (pairs of elems, 8 sc01 loads in flight) ---
    #pragma unroll
    for (int k = 0; k < 5; ++k){
      int e1 = tid + (2*k)*512, e2 = tid + (2*k+1)*512;
      int r1 = e1/320, c1 = e1 - 320*r1, h1 = c1 >> 5, d1 = c1 & 31;
      int r2 = e2/320, c2 = e2 - 320*r2, h2 = c2 >> 5, d2 = c2 & 31;
      const float* p1 = part + (((size_t)h1*MAXCH_)*K_ + r0 + r1)*36 + d1;
      const float* p2 = part + (((size_t)h2*MAXCH_)*K_ + r0 + r2)*36 + d2;
      float a0=0.f,a1=0.f,a2_=0.f,a3=0.f,b0=0.f,b1=0.f,b2=0.f,b3=0.f;
      int ci = 0;
      for (; ci + 4 <= nch; ci += 4){
        float x0,x1,x2,x3,y0,y1,y2,y3;
        LD1(x0, p1+(ci+0)*4608); LD1(x1, p1+(ci+1)*4608);
        LD1(x2, p1+(ci+2)*4608); LD1(x3, p1+(ci+3)*4608);
        LD1(y0, p2+(ci+0)*4608); LD1(y1, p2+(ci+1)*4608);
        LD1(y2, p2+(ci+2)*4608); LD1(y3, p2+(ci+3)*4608);
        WD8(x0,x1,x2,x3,y0,y1,y2,y3);
        a0 += mlw[r1][h1][ci+0]*x0; a1 += mlw[r1][h1][ci+1]*x1;
        a2_+= mlw[r1][h1][ci+2]*x2; a3 += mlw[r1][h1][ci+3]*x3;
        b0 += mlw[r2][h2][ci+0]*y0; b1 += mlw[r2][h2][ci+1]*y1;
        b2 += mlw[r2][h2][ci+2]*y2; b3 += mlw[r2][h2][ci+3]*y3;
      }
      for (; ci < nch; ++ci){
        float x0,y0;
        LD1(x0, p1+ci*4608); LD1(y0, p2+ci*4608);
        WD2(x0,y0);
        a0 += mlw[r1][h1][ci]*x0;
        b0 += mlw[r2][h2][ci]*y0;
      }
      af[r1][c1] = __float2bfloat16(((a0+a1)+(a2_+a3)) / mlL[r1][h1]);
      af[r2][c2] = __float2bfloat16(((b0+b1)+(b2+b3)) / mlL[r2][h2]);
    }
    __syncthreads();

    // --- out-proj MFMA: xbuf(16x320) = af . out_w^T + outb + residual ---
    {
      f32x4 acc[3]; int ntv[3]; int ntc = 0;
      for (int nt = w; nt < 20; nt += 8){ ntv[ntc] = nt; acc[ntc] = (f32x4){0.f,0.f,0.f,0.f}; ntc++; }
      for (int kk = 0; kk < 10; ++kk){
        short8 afr = *(const short8*)(const void*)(&af[cn][kk*32 + quad*8]);
        for (int i = 0; i < ntc; ++i){
          short8 bfr = *(const short8*)(const void*)(owB + ((size_t)(ntv[i]*16 + cn))*E_ + kk*32 + quad*8);
          acc[i] = __builtin_amdgcn_mfma_f32_16x16x32_bf16(afr, bfr, acc[i], 0, 0, 0);
        }
      }
      __syncthreads();   // af fully read; xbuf (overlaying mlw) now writable
      for (int i = 0; i < ntc; ++i){
        int col = ntv[i]*16 + cn;
        float rv0,rv1,rv2,rv3;
        LD1(rv0, ain + (size_t)(r0+quad*4+0)*E_ + col);
        LD1(rv1, ain + (size_t)(r0+quad*4+1)*E_ + col);
        LD1(rv2, ain + (size_t)(r0+quad*4+2)*E_ + col);
        LD1(rv3, ain + (size_t)(r0+quad*4+3)*E_ + col);
        WD4(rv0,rv1,rv2,rv3);
        float vb = vec[col];
        xbuf[quad*4+0][col] = acc[i][0] + vb + rv0;
        xbuf[quad*4+1][col] = acc[i][1] + vb + rv1;
        xbuf[quad*4+2][col] = acc[i][2] + vb + rv2;
        xbuf[quad*4+3][col] = acc[i][3] + vb + rv3;
      }
    }
    __syncthreads();

    // --- LN per row ---
    {
      int lr = tid >> 5;
      int j32 = tid & 31;
      float s = 0.f, s2 = 0.f;
      for (int c = j32; c < E_; c += 32){ float x = xbuf[lr][c]; s += x; s2 += x*x; }
      #pragma unroll
      for (int off = 1; off < 32; off <<= 1){
        s  += __shfl_xor(s, off, 32);
        s2 += __shfl_xor(s2, off, 32);
      }
      float mean = s * (1.f/E_);
      float var  = s2 * (1.f/E_) - mean*mean;
      float rs = rsqrtf(var + EPS_LN);
      for (int c = j32; c < E_; c += 32){
        float y = (xbuf[lr][c] - mean) * rs * vec[320 + c] + vec[640 + c];
        a2[lr][c] = __float2bfloat16(y);
        if (cg == 0){
          st_sc_f32(aout + (size_t)(r0+lr)*E_ + c, y);
          stout(out, ((size_t)t*K_ + r0 + lr)*E_ + c, y, isbf);
        }
      }
    }
    __syncthreads();
  } else {
    // t == 0: alpha straight from ln0 (one-time; serialized sc01 loads fine)
    for (int v = tid; v < 16*E_; v += 512){
      int r = v / E_, e = v - E_*(v/E_);
      float x; LD1(x, ain + (size_t)(r0+r)*E_ + e); WD1(x);
      a2[r][e] = __float2bfloat16(x);
    }
    __syncthreads();
  }

  if (!do_project) return;

  // --- project MFMA: this cg's 320 of the 960 output cols ---
  {
    f32x4 acc[3]; int ntv[3]; int ntc = 0;
    for (int nt = w; nt < 20; nt += 8){ ntv[ntc] = nt; acc[ntc] = (f32x4){0.f,0.f,0.f,0.f}; ntc++; }
    for (int kk = 0; kk < 10; ++kk){
      short8 afr = *(const short8*)(const void*)(&a2[cn][kk*32 + quad*8]);
      for (int i = 0; i < ntc; ++i){
        short8 bfr = *(const short8*)(const void*)(WcB + ((size_t)(cg*E_ + ntv[i]*16 + cn))*E_ + kk*32 + quad*8);
        acc[i] = __builtin_amdgcn_mfma_f32_16x16x32_bf16(afr, bfr, acc[i], 0, 0, 0);
      }
    }
    for (int i = 0; i < ntc; ++i){
      int coll = ntv[i]*16 + cn;
      float bias = bc[cg*E_ + coll];
      if (cg == 0){
        #pragma unroll
        for (int rr = 0; rr < 4; ++rr)
          st_sc_bf16(q2b + (size_t)(r0 + quad*4 + rr)*E_ + coll, acc[i][rr] + bias);
      } else if (cg == 1){
        #pragma unroll
        for (int rr = 0; rr < 4; ++rr)
          st_sc_bf16(kcb + ((size_t)(t*K_ + r0 + quad*4 + rr))*E_ + coll, acc[i][rr] + bias);
      } else {
        union { short4v v; bf16 e[4]; } u;
        #pragma unroll
        for (int rr = 0; rr < 4; ++rr) u.e[rr] = __float2bfloat16(acc[i][rr] + bias);
        st_sc_b64(vtb + (size_t)coll*SMAX_ + t*K_ + r0 + quad*4, u.v);
      }
    }
  }
}

// ---- one attention cell (ci,h): 8 waves, wave w owns q-tile w ----
__device__ __forceinline__ void attn_cell(int ci, int h, const bf16* q2b, const bf16* kcb,
                                          const bf16* vtb, float* part, int S, int chunkS,
                                          char* smem){
  int w    = threadIdx.x >> 6;
  int lane = threadIdx.x & 63;
  int cn   = lane & 15;
  int quad = lane >> 4;
  bf16 (*pbuf)[40] = (bf16(*)[40])(smem + w*16*40*2);

  int s0 = ci*chunkS, s1 = min(s0 + chunkS, S);

  short8 qf;
  LD4(qf, q2b + (size_t)(w*16 + cn)*E_ + h*HD_ + quad*8);
  WD1(qf);

  f32x4 accT[2];
  accT[0] = (f32x4){0.f,0.f,0.f,0.f};
  accT[1] = (f32x4){0.f,0.f,0.f,0.f};
  float mcol = -INFINITY, lcol = 0.f;

  for (int sb = s0; sb < s1; sb += 32){
    // KV loads stay normal-cached (write-once rows; L2 reuse across steps)
    short8 kf0 = *(const short8*)(const void*)(kcb + (size_t)(sb +      cn)*E_ + h*HD_ + quad*8);
    short8 kf1 = *(const short8*)(const void*)(kcb + (size_t)(sb + 16 + cn)*E_ + h*HD_ + quad*8);
    short8 vf0 = *(const short8*)(const void*)(vtb + (size_t)(h*HD_ +      cn)*SMAX_ + sb + quad*8);
    short8 vf1 = *(const short8*)(const void*)(vtb + (size_t)(h*HD_ + 16 + cn)*SMAX_ + sb + quad*8);
    f32x4 z = (f32x4){0.f,0.f,0.f,0.f};
    f32x4 sT0 = __builtin_amdgcn_mfma_f32_16x16x32_bf16(kf0, qf, z, 0, 0, 0);
    f32x4 sT1 = __builtin_amdgcn_mfma_f32_16x16x32_bf16(kf1, qf, z, 0, 0, 0);

    float mx = fmaxf(fmaxf(fmaxf(sT0[0], sT0[1]), fmaxf(sT0[2], sT0[3])),
                     fmaxf(fmaxf(sT1[0], sT1[1]), fmaxf(sT1[2], sT1[3])));
    mx = fmaxf(mx, __shfl_xor(mx, 16, 64));
    mx = fmaxf(mx, __shfl_xor(mx, 32, 64));
    float mn = fmaxf(mcol, mx);
    float corr = __expf(mcol - mn);
    mcol = mn;

    float p0[4], p1[4];
    #pragma unroll
    for (int r = 0; r < 4; ++r){ p0[r] = __expf(sT0[r] - mn); p1[r] = __expf(sT1[r] - mn); }
    float ps = (p0[0]+p0[1]) + (p0[2]+p0[3]) + (p1[0]+p1[1]) + (p1[2]+p1[3]);
    ps += __shfl_xor(ps, 16, 64);
    ps += __shfl_xor(ps, 32, 64);
    lcol = lcol*corr + ps;
    accT[0] *= corr;
    accT[1] *= corr;

    union { short4v v; bf16 e[4]; } u0, u1;
    #pragma unroll
    for (int r = 0; r < 4; ++r){ u0.e[r] = __float2bfloat16(p0[r]); u1.e[r] = __float2bfloat16(p1[r]); }
    *(short4v*)(void*)(&pbuf[cn][quad*4])      = u0.v;
    *(short4v*)(void*)(&pbuf[cn][16 + quad*4]) = u1.v;
    asm volatile("s_waitcnt lgkmcnt(0)" ::: "memory");
    short8 pf = *(const short8*)(const void*)(&pbuf[cn][quad*8]);
    accT[0] = __builtin_amdgcn_mfma_f32_16x16x32_bf16(vf0, pf, accT[0], 0, 0, 0);
    accT[1] = __builtin_amdgcn_mfma_f32_16x16x32_bf16(vf1, pf, accT[1], 0, 0, 0);
  }

  size_t base = (((size_t)h*MAXCH_ + ci)*K_ + 16*w + cn)*36;
  st_sc_f32x4(part + base + quad*4,      accT[0]);
  st_sc_f32x4(part + base + 16 + quad*4, accT[1]);
  if (quad == 0){
    st_sc_f32(part + base + 32, mcol);
    st_sc_f32(part + base + 33, lcol);
  }
}

// ---------------- persistent scan kernel: 256 blocks x 512 threads ----------------
__global__ __launch_bounds__(512) void mega_kernel(const bf16* WcB, const bf16* owB,
                                                   const float* bc, const float* vec,
                                                   float* abuf0, float* abuf1,
                                                   float* part, const int* flagp,
                                                   bf16* q2b, bf16* kcb, bf16* vtb,
                                                   void* out,
                                                   unsigned* bar_cnt, unsigned* bar_gen){
  __shared__ __align__(16) char smem[SM_SIZE];
  const int isbf = *flagp;
  int b = blockIdx.x;
  int cg = b / 8, rg = b - 8*(b/8);   // for b<24

  int nch_prev = 0;
  for (int t = 0; t < TM1_; ++t){
    const float* ain = (t == 0) ? abuf0 : ((t & 1) ? abuf0 : abuf1);
    float* aout = (t & 1) ? abuf1 : abuf0;
    if (b < 24)
      cp_phase(cg, rg, t, nch_prev, (t > 0) ? 1 : 0, 1,
               part, owB, WcB, bc, vec, ain, aout, out, isbf, q2b, kcb, vtb, smem);
    grid_barrier(bar_cnt, bar_gen);

    int S = (t+1)*K_;
    int nch = (S + 127) / 128; if (nch > MAXCH_) nch = MAXCH_;
    int chunkS = (((S + nch - 1)/nch) + 31) / 32 * 32;
    int nchU = (S + chunkS - 1) / chunkS;
    if (b < nchU*10)
      attn_cell(b/10, b - 10*(b/10), q2b, kcb, vtb, part, S, chunkS, smem);
    grid_barrier(bar_cnt, bar_gen);
    nch_prev = nchU;
  }
  // final combine: alpha(255) -> out rows 255*K (blocks 0..7, cg==0)
  if (b < 8){
    const float* ain = abuf0;   // alpha(254): t=254 even -> aout was abuf0
    float* aout = abuf1;
    cp_phase(0, b, TM1_, nch_prev, 1, 0,
             part, owB, WcB, bc, vec, ain, aout, out, isbf, q2b, kcb, vtb, smem);
  }
}

extern "C" void kernel_launch(void* const* d_in, const int* in_sizes, int n_in,
                              void* d_out, int out_size, void* d_ws, size_t ws_size,
                              hipStream_t stream){
  const void* mu0  = d_in[0];
  const void* qkvw = d_in[1];
  const void* qkvb = d_in[2];
  const void* inw  = d_in[3];
  const void* inb  = d_in[4];
  const void* outw = d_in[5];
  const void* outb = d_in[6];
  const void* lng  = d_in[7];
  const void* lnb  = d_in[8];
  float* ws = (float*)d_ws;

  // ws layout (float offsets), all 16B-aligned
  const size_t O_WCB    = 0;         // 960x320 bf16 = 153600 f
  const size_t O_OWB    = 153600;    // 320x320 bf16 = 51200 f
  const size_t O_BC     = 204800;    // 1024
  const size_t O_VEC    = 205824;    // 1024
  const size_t O_A0     = 206848;    // 40960
  const size_t O_A1     = 247808;    // 40960
  const size_t O_PART   = 288768;    // 10*25*128*36 = 1152000
  const size_t O_FLAG   = 1440768;   // flag @0, bar_cnt @32, bar_gen @64
  const size_t O_Q2     = 1440864;   // 128*320 bf16 = 20480 f
  const size_t O_KC     = 1461344;   // SMAX*320 bf16 = 5222400 f
  const size_t O_VT     = 6683744;   // SMAX*320 bf16 = 5222400 f
  // end = 11906144 floats = 47.6 MB

  bf16*  WcB   = (bf16*)(ws + O_WCB);
  bf16*  owB   = (bf16*)(ws + O_OWB);
  float* bc    = ws + O_BC;
  float* vec   = ws + O_VEC;
  float* abuf0 = ws + O_A0;
  float* abuf1 = ws + O_A1;
  float* part  = ws + O_PART;
  int*   flag  = (int*)(ws + O_FLAG);
  unsigned* bar_cnt = (unsigned*)(ws + O_FLAG + 32);
  unsigned* bar_gen = (unsigned*)(ws + O_FLAG + 64);
  bf16*  q2b   = (bf16*)(ws + O_Q2);
  bf16*  kcb   = (bf16*)(ws + O_KC);
  bf16*  vtb   = (bf16*)(ws + O_VT);

  detect_kernel<<<dim3(1), dim3(64), 0, stream>>>(mu0, flag, bar_cnt, bar_gen);
  setup_wc<<<dim3(20,20,3), dim3(16,16), 0, stream>>>(inw, qkvw, WcB, flag);
  setup_misc<<<dim3(408), dim3(256), 0, stream>>>(inw, inb, qkvb, outw, outb, lng, lnb, bc, owB, vec, flag);
  ln0_kernel<<<dim3(128), dim3(320), 0, stream>>>(mu0, vec, abuf0, d_out, flag);
  mega_kernel<<<dim3(NBLK_), dim3(512), 0, stream>>>(WcB, owB, bc, vec, abuf0, abuf1,
                                                     part, flag, q2b, kcb, vtb, d_out,
                                                     bar_cnt, bar_gen);
}